// Round 4
// baseline (419.414 us; speedup 1.0000x reference)
//
#include <hip/hip_runtime.h>
#include <cstddef>

// Problem constants
#define NROWS 8192   // B*L
#define LLEN  4096
#define KNBR  32
#define DIMX  256
#define PEDIM 64
#define NH    8
#define QKVLD 768    // Q(256) | KtX(256) | VtX(256)

// ---------------------------------------------------------------------------
// fp32 GEMM: BM=128, BN=64, BK=16, 128 threads (2 waves), 8x8 micro-tile.
// Micro-tile rows {ty*4+i, 64+ty*4+i}, cols {tx*4+j, 32+tx*4+j} -> all LDS
// reads conflict-free. As k-major [16][132] (row = 528 B = 33*16, f4-aligned).
// B selected per column-block (qkv fusion): by<4 -> B0, <8 -> B1, else B2.
// ---------------------------------------------------------------------------
__global__ __launch_bounds__(128)
void gemm_f32(const float* __restrict__ A, int lda,
              const float* __restrict__ B0, const float* __restrict__ B1,
              const float* __restrict__ B2, int ldb,
              const float* __restrict__ bias,
              float* __restrict__ C, int ldc, int Kd)
{
    __shared__ float As[16][132];
    __shared__ float Bs[16][68];
    const int t  = threadIdx.x;
    const int m0 = blockIdx.x * 128;
    const int by = blockIdx.y;
    const int n0 = by * 64;
    const float* Bm = (by < 4) ? B0 : (by < 8) ? B1 : B2;
    const int nb = (by & 3) * 64;
    const int tx = t & 7, ty = t >> 3;

    float acc[8][8] = {};
    float4 av[4], bv[2];
    const float* Arow = A + (size_t)(m0 + t) * lda;

    // prologue: stage tile k0=0 into registers
#pragma unroll
    for (int q = 0; q < 4; ++q) av[q] = *(const float4*)&Arow[q * 4];
#pragma unroll
    for (int p = 0; p < 2; ++p) {
        const int id = t + p * 128, kq = id >> 4, c4 = id & 15;
        bv[p] = *(const float4*)&Bm[(size_t)kq * ldb + nb + c4 * 4];
    }

    for (int k0 = 0; k0 < Kd; k0 += 16) {
        // regs -> LDS
#pragma unroll
        for (int q = 0; q < 4; ++q) {
            As[q * 4 + 0][t] = av[q].x; As[q * 4 + 1][t] = av[q].y;
            As[q * 4 + 2][t] = av[q].z; As[q * 4 + 3][t] = av[q].w;
        }
#pragma unroll
        for (int p = 0; p < 2; ++p) {
            const int id = t + p * 128, kq = id >> 4, c4 = id & 15;
            *(float4*)&Bs[kq][c4 * 4] = bv[p];
        }
        __syncthreads();
        // prefetch next tile (overlaps with compute below)
        if (k0 + 16 < Kd) {
#pragma unroll
            for (int q = 0; q < 4; ++q)
                av[q] = *(const float4*)&Arow[k0 + 16 + q * 4];
#pragma unroll
            for (int p = 0; p < 2; ++p) {
                const int id = t + p * 128, kq = id >> 4, c4 = id & 15;
                bv[p] = *(const float4*)&Bm[(size_t)(k0 + 16 + kq) * ldb + nb + c4 * 4];
            }
        }
#pragma unroll
        for (int kk = 0; kk < 16; ++kk) {
            float4 a0 = *(const float4*)&As[kk][ty * 4];
            float4 a1 = *(const float4*)&As[kk][64 + ty * 4];
            float4 b0 = *(const float4*)&Bs[kk][tx * 4];
            float4 b1 = *(const float4*)&Bs[kk][32 + tx * 4];
            float ar[8] = {a0.x, a0.y, a0.z, a0.w, a1.x, a1.y, a1.z, a1.w};
            float br[8] = {b0.x, b0.y, b0.z, b0.w, b1.x, b1.y, b1.z, b1.w};
#pragma unroll
            for (int i = 0; i < 8; ++i)
#pragma unroll
                for (int j = 0; j < 8; ++j)
                    acc[i][j] += ar[i] * br[j];
        }
        __syncthreads();
    }

#pragma unroll
    for (int ih = 0; ih < 2; ++ih)
#pragma unroll
    for (int i = 0; i < 4; ++i) {
        const int row = m0 + ih * 64 + ty * 4 + i;
#pragma unroll
        for (int jh = 0; jh < 2; ++jh) {
            const int col = n0 + jh * 32 + tx * 4;
            float4 o;
            o.x = acc[ih * 4 + i][jh * 4 + 0] + (bias ? bias[col + 0] : 0.f);
            o.y = acc[ih * 4 + i][jh * 4 + 1] + (bias ? bias[col + 1] : 0.f);
            o.z = acc[ih * 4 + i][jh * 4 + 2] + (bias ? bias[col + 2] : 0.f);
            o.w = acc[ih * 4 + i][jh * 4 + 3] + (bias ? bias[col + 3] : 0.f);
            *(float4*)&C[(size_t)row * ldc + col] = o;
        }
    }
}

// ---------------------------------------------------------------------------
// Fused attention. 128 threads = 2 waves, 2 rows/WG (one row per wave).
// rpe staged ONCE in LDS (read coalesced, reused by logits + u_pe phases).
// Buffer unions: QsOx (Q then o_x), TrUs (rpe-key-fold then u_pe).
// LDS = 25.5 KB -> 6 blocks/CU.
// ---------------------------------------------------------------------------
__global__ __launch_bounds__(128)
void attn_fused(const float* QKV, const int* __restrict__ topk,
                const float* __restrict__ rpe, const float* __restrict__ dist,
                const float* __restrict__ lsig,
                const float* __restrict__ Wk, const float* __restrict__ Wv,
                float* O)
{
    __shared__ float QsOx[2][256];        // 2 KB   Q row -> o_x
    __shared__ float TrUs[2][NH][68];     // 4.25 KB Tr -> u_pe (pad 68)
    __shared__ float As2[2][KNBR][8];     // 2 KB   attn [row][k][h]
    __shared__ float rpeS[2][KNBR][68];   // 17 KB  rpe rows (pad 68)
    __shared__ int   tkS[2][KNBR];        // 256 B

    const int t = threadIdx.x, w = t >> 6, lane = t & 63;
    const int r0 = blockIdx.x * 2, r = r0 + w;
    const int b = r >> 12;                 // r / LLEN
    const float scale = 0.17677669529663687f;  // 32^-0.5

    // ---- phase 1: stage Q row, rpe row, topk row (all coalesced) ----
    *(float4*)&QsOx[w][lane * 4] = *(const float4*)&QKV[(size_t)r * QKVLD + lane * 4];
#pragma unroll
    for (int p = 0; p < 8; ++p) {
        const int g = p * 64 + lane;       // f4 id 0..511, contiguous
        const int k = g >> 4, c4 = g & 15;
        *(float4*)&rpeS[w][k][c4 * 4] =
            *(const float4*)&rpe[((size_t)r * KNBR + k) * PEDIM + c4 * 4];
    }
    if (lane < KNBR) tkS[w][lane] = topk[r * KNBR + lane];
    __syncthreads();

    // ---- phase 2: Tr[i][h][c] = sum_d Qs[i][h*32+d] * Wk[(256+c)*256+h*32+d]
    {
        const int h = t >> 4, cl = t & 15;
#pragma unroll
        for (int i = 0; i < 2; ++i) {
            float4 q[8];
#pragma unroll
            for (int j = 0; j < 8; ++j)
                q[j] = *(const float4*)&QsOx[i][h * 32 + j * 4];
#pragma unroll
            for (int cc = 0; cc < 4; ++cc) {
                const int c = cl + cc * 16;
                const float4* wp = (const float4*)&Wk[(size_t)(256 + c) * 256 + h * 32];
                float s = 0.f;
#pragma unroll
                for (int j = 0; j < 8; ++j) {
                    float4 wv_ = wp[j];
                    s += q[j].x * wv_.x + q[j].y * wv_.y + q[j].z * wv_.z + q[j].w * wv_.w;
                }
                TrUs[i][h][c] = s;
            }
        }
    }
    __syncthreads();

    // ---- phase 3: logits + softmax (wave-local row) ----
    const int kk = lane & 31, hh = lane >> 5;
    {
        const int myidx = tkS[w][kk];
        const float* ktrow = &QKV[(size_t)(b * LLEN + myidx) * QKVLD + 256];
        float acc4[4];
#pragma unroll
        for (int i = 0; i < 4; ++i) {
            const int h = hh * 4 + i;
            const float4* qp = (const float4*)&QsOx[w][h * 32];
            const float4* kp = (const float4*)&ktrow[h * 32];
            float s = 0.f;
#pragma unroll
            for (int j = 0; j < 8; ++j) {
                float4 q = qp[j], kv = kp[j];
                s += q.x * kv.x + q.y * kv.y + q.z * kv.z + q.w * kv.w;
            }
            acc4[i] = s;
        }
#pragma unroll 4
        for (int c4 = 0; c4 < 16; ++c4) {
            float4 rv = *(const float4*)&rpeS[w][kk][c4 * 4];
#pragma unroll
            for (int i = 0; i < 4; ++i) {
                float4 tv = *(const float4*)&TrUs[w][hh * 4 + i][c4 * 4];
                acc4[i] += rv.x * tv.x + rv.y * tv.y + rv.z * tv.z + rv.w * tv.w;
            }
        }
        const float dd = dist[r * KNBR + kk];
        const float d2 = dd * dd;
#pragma unroll
        for (int i = 0; i < 4; ++i) {
            const int h = hh * 4 + i;
            const float sig2 = __expf(2.f * lsig[h]);
            float lg = acc4[i] * scale - d2 / (2.f * sig2);
            float mx = lg;
#pragma unroll
            for (int m = 16; m >= 1; m >>= 1)
                mx = fmaxf(mx, __shfl_xor(mx, m, 64));
            float pv = __expf(lg - mx);
            float sm = pv;
#pragma unroll
            for (int m = 16; m >= 1; m >>= 1)
                sm += __shfl_xor(sm, m, 64);
            As2[w][kk][h] = pv / sm;
        }
    }
    // As2[w]/rpeS[w]/TrUs[w]/QsOx[w] are wave-local from here: no barrier.

    // ---- phase 4: o_x = sum_k attn * VtX[idx_k]  (overwrites Qs slot) ----
    {
        const int h2 = lane >> 3;                 // head of column lane*4
        const float* vbase = &QKV[(size_t)b * LLEN * QKVLD + 512 + lane * 4];
        float4 ox = {0.f, 0.f, 0.f, 0.f};
#pragma unroll 8
        for (int k = 0; k < KNBR; ++k) {
            const int ik = tkS[w][k];             // wave-uniform
            float4 vv = *(const float4*)&vbase[(size_t)ik * QKVLD];
            const float aw = As2[w][k][h2];
            ox.x += aw * vv.x; ox.y += aw * vv.y;
            ox.z += aw * vv.z; ox.w += aw * vv.w;
        }
        *(float4*)&QsOx[w][lane * 4] = ox;
    }

    // ---- phase 5: u_pe[h][c] = sum_k attn[h,k]*rpe[k,c] (overwrites Tr) ----
    {
        float u[8] = {};
#pragma unroll 8
        for (int k = 0; k < KNBR; ++k) {
            const float rv = rpeS[w][k][lane];    // 2-way bank (free)
            float4 a0 = *(const float4*)&As2[w][k][0];
            float4 a1 = *(const float4*)&As2[w][k][4];
            u[0] += a0.x * rv; u[1] += a0.y * rv; u[2] += a0.z * rv; u[3] += a0.w * rv;
            u[4] += a1.x * rv; u[5] += a1.y * rv; u[6] += a1.z * rv; u[7] += a1.w * rv;
        }
#pragma unroll
        for (int h = 0; h < NH; ++h) TrUs[w][h][lane] = u[h];
    }
    __syncthreads();

    // ---- phase 6: o_pe + combine; thread covers cols {t, t+128}, both rows
#pragma unroll
    for (int half = 0; half < 2; ++half) {
        const int n = t + half * 128;
        const int hn = n >> 5;
        float accp0 = 0.f, accp1 = 0.f;
#pragma unroll 4
        for (int c4 = 0; c4 < 16; ++c4) {
            float4 u0 = *(const float4*)&TrUs[0][hn][c4 * 4];
            float4 u1 = *(const float4*)&TrUs[1][hn][c4 * 4];
            const float* wvp = &Wv[(size_t)(256 + c4 * 4) * 256 + n];
            const float w0 = wvp[0], w1 = wvp[256], w2 = wvp[512], w3 = wvp[768];
            accp0 += u0.x * w0 + u0.y * w1 + u0.z * w2 + u0.w * w3;
            accp1 += u1.x * w0 + u1.y * w1 + u1.z * w2 + u1.w * w3;
        }
        O[(size_t)(r0 + 0) * QKVLD + n] = QsOx[0][n] + accp0;
        O[(size_t)(r0 + 1) * QKVLD + n] = QsOx[1][n] + accp1;
    }
}

// ---------------------------------------------------------------------------
extern "C" void kernel_launch(void* const* d_in, const int* in_sizes, int n_in,
                              void* d_out, int out_size, void* d_ws, size_t ws_size,
                              hipStream_t stream)
{
    const float* x     = (const float*)d_in[0];
    const int*   topk  = (const int*)  d_in[1];
    const float* rpe   = (const float*)d_in[2];
    const float* dist  = (const float*)d_in[3];
    const float* Wq    = (const float*)d_in[4];
    const float* Wk    = (const float*)d_in[5];
    const float* Wv    = (const float*)d_in[6];
    const float* Wout  = (const float*)d_in[7];
    const float* b_out = (const float*)d_in[8];
    const float* lsig  = (const float*)d_in[9];
    float* out = (float*)d_out;

    float* QKV = (float*)d_ws;   // 8192 x 768 f32 = 24 MB

    // K1: QKV = x @ [Wq | Wk_x | Wv_x]   (grid 64 x 12 = 768 blocks)
    gemm_f32<<<dim3(NROWS / 128, QKVLD / 64), 128, 0, stream>>>(
        x, DIMX, Wq, Wk, Wv, DIMX, nullptr, QKV, QKVLD, DIMX);
    // K2: fused attention; o overwrites the Q slice of QKV
    attn_fused<<<NROWS / 2, 128, 0, stream>>>(QKV, topk, rpe, dist, lsig, Wk, Wv, QKV);
    // K3: out = o @ Wout + b_out         (grid 64 x 4 = 256 blocks)
    gemm_f32<<<dim3(NROWS / 128, DIMX / 64), 128, 0, stream>>>(
        QKV, QKVLD, Wout, Wout, Wout, DIMX, b_out, out, DIMX, DIMX);
}

// Round 5
// 307.254 us; speedup vs baseline: 1.3650x; 1.3650x over previous
//
#include <hip/hip_runtime.h>
#include <cstddef>

// Problem constants
#define NROWS 8192   // B*L
#define LLEN  4096
#define KNBR  32
#define DIMX  256
#define PEDIM 64
#define NH    8
#define QKVLD 768    // Q(256) | KtX(256) | VtX(256)

// ---------------------------------------------------------------------------
// K1: QKV = x @ [Wq | Wk_x | Wv_x].  128x128 tiles, BK=16, 256 thr (4 waves),
// 8x8 micro-tile, register-double-buffered global loads.
// A-load: 2 lanes per row (full 64B line use). As k-major [16][136] (writes
// 2 lanes/bank = free; reads broadcast). Bs [16][132] (contiguous = free).
// ---------------------------------------------------------------------------
__global__ __launch_bounds__(256)
void gemm_qkv(const float* __restrict__ A,
              const float* __restrict__ B0, const float* __restrict__ B1,
              const float* __restrict__ B2,
              float* __restrict__ C)
{
    __shared__ float As[16][136];
    __shared__ float Bs[16][132];
    const int t  = threadIdx.x;
    const int m0 = blockIdx.x * 128;
    const int by = blockIdx.y;                 // 0..5
    const float* Bm = (by < 2) ? B0 : (by < 4) ? B1 : B2;
    const int nb = (by & 1) * 128;
    const int n0 = by * 128;
    const int tx = t & 15, ty = t >> 4;
    const int lm = t >> 1, ks = (t & 1) * 8;   // A: row lm, k-offset ks(+0..7)
    const int bn = t & 31, bk = t >> 5;        // B: rows bk, bk+8; f4-col bn

    float acc[8][8] = {};
    const float* Arow = A + (size_t)(m0 + lm) * DIMX + ks;
    float4 a0v = *(const float4*)&Arow[0];
    float4 a1v = *(const float4*)&Arow[4];
    float4 b0v = *(const float4*)&Bm[(size_t)bk * DIMX + nb + bn * 4];
    float4 b1v = *(const float4*)&Bm[(size_t)(bk + 8) * DIMX + nb + bn * 4];

    for (int k0 = 0; k0 < DIMX; k0 += 16) {
        As[ks+0][lm]=a0v.x; As[ks+1][lm]=a0v.y; As[ks+2][lm]=a0v.z; As[ks+3][lm]=a0v.w;
        As[ks+4][lm]=a1v.x; As[ks+5][lm]=a1v.y; As[ks+6][lm]=a1v.z; As[ks+7][lm]=a1v.w;
        *(float4*)&Bs[bk][bn*4]     = b0v;
        *(float4*)&Bs[bk+8][bn*4]   = b1v;
        __syncthreads();
        if (k0 + 16 < DIMX) {                  // prefetch next K-tile
            a0v = *(const float4*)&Arow[k0 + 16];
            a1v = *(const float4*)&Arow[k0 + 20];
            b0v = *(const float4*)&Bm[(size_t)(k0 + 16 + bk) * DIMX + nb + bn * 4];
            b1v = *(const float4*)&Bm[(size_t)(k0 + 24 + bk) * DIMX + nb + bn * 4];
        }
#pragma unroll
        for (int kk = 0; kk < 16; ++kk) {
            float4 a0 = *(const float4*)&As[kk][ty * 4];
            float4 a1 = *(const float4*)&As[kk][64 + ty * 4];
            float4 b0 = *(const float4*)&Bs[kk][tx * 4];
            float4 b1 = *(const float4*)&Bs[kk][64 + tx * 4];
            float ar[8] = {a0.x, a0.y, a0.z, a0.w, a1.x, a1.y, a1.z, a1.w};
            float br[8] = {b0.x, b0.y, b0.z, b0.w, b1.x, b1.y, b1.z, b1.w};
#pragma unroll
            for (int i = 0; i < 8; ++i)
#pragma unroll
                for (int j = 0; j < 8; ++j)
                    acc[i][j] += ar[i] * br[j];
        }
        __syncthreads();
    }

#pragma unroll
    for (int ih = 0; ih < 2; ++ih)
#pragma unroll
    for (int i = 0; i < 4; ++i) {
        const int row = m0 + ih * 64 + ty * 4 + i;
#pragma unroll
        for (int jh = 0; jh < 2; ++jh) {
            const int col = n0 + jh * 64 + tx * 4;
            *(float4*)&C[(size_t)row * QKVLD + col] =
                make_float4(acc[ih*4+i][jh*4+0], acc[ih*4+i][jh*4+1],
                            acc[ih*4+i][jh*4+2], acc[ih*4+i][jh*4+3]);
        }
    }
}

// ---------------------------------------------------------------------------
// K2: fused attention + output projection. 256 thr (4 waves), 1 row/wave.
// Phases P1-P5 are wave-local (only 2 barriers in the whole kernel):
//  P1 stage Q,topk   P2 Tr[h,c]=Q.Wk_pe (lane=c)   P3 logits+softmax
//  P4 o_x = sum_k attn*VtX[idx]   P5 u_pe = sum_k attn*rpe  | barrier
//  P6 o = o_x + u_pe@Wv_pe        | barrier
//  P7 out = o@Wout + b_out  (fused K3: rides the latency-idle VALU)
// LDS 17.4 KB; unions QsO (Q->o), TrUs (Tr->u_pe).
// ---------------------------------------------------------------------------
__global__ __launch_bounds__(256)
void attn_fused(const float* QKV, const int* __restrict__ topk,
                const float* __restrict__ rpe, const float* __restrict__ dist,
                const float* __restrict__ lsig,
                const float* __restrict__ Wk, const float* __restrict__ Wv,
                const float* __restrict__ Wout, const float* __restrict__ b_out,
                float* __restrict__ out)
{
    __shared__ float QsO[4][260];          // 4.1 KB  Q row -> o row
    __shared__ float TrUs[4][NH][68];      // 8.5 KB  Tr -> u_pe
    __shared__ float As2[4][KNBR][NH];     // 4 KB    attn [row][k][h]
    __shared__ int   tkS[4][KNBR];         // 0.5 KB

    const int t = threadIdx.x, w = t >> 6, lane = t & 63;
    const int r0 = blockIdx.x * 4, r = r0 + w;
    const int b = r >> 12;                 // r / LLEN
    const float scale = 0.17677669529663687f;  // 32^-0.5

    // ---- P1: stage own Q row + topk (wave-local) ----
    *(float4*)&QsO[w][lane * 4] = *(const float4*)&QKV[(size_t)r * QKVLD + lane * 4];
    if (lane < KNBR) tkS[w][lane] = topk[r * KNBR + lane];

    // ---- P2: Tr[h][c] = Q[h,:].Wk_pe[c,h-slice], lane = c (wave-local) ----
    {
        const int c = lane;
#pragma unroll
        for (int h = 0; h < NH; ++h) {
            const float4* wp = (const float4*)&Wk[(size_t)(256 + c) * 256 + h * 32];
            const float4* qp = (const float4*)&QsO[w][h * 32];
            float s = 0.f;
#pragma unroll
            for (int j = 0; j < 8; ++j) {
                float4 wv_ = wp[j], q = qp[j];
                s += q.x * wv_.x + q.y * wv_.y + q.z * wv_.z + q.w * wv_.w;
            }
            TrUs[w][h][c] = s;
        }
    }

    // ---- P3: logits + softmax (wave-local; lane = (kk, hh)) ----
    const int kk = lane & 31, hh = lane >> 5;
    {
        const int my = tkS[w][kk];
        const float* ktrow = &QKV[(size_t)(b * LLEN + my) * QKVLD + 256];
        const float* rrow  = &rpe[((size_t)r * KNBR + kk) * PEDIM];
        float acc4[4];
#pragma unroll
        for (int i = 0; i < 4; ++i) {
            const int h = hh * 4 + i;
            const float4* qp = (const float4*)&QsO[w][h * 32];
            const float4* kp = (const float4*)&ktrow[h * 32];
            float s = 0.f;
#pragma unroll
            for (int j = 0; j < 8; ++j) {
                float4 q = qp[j], kv = kp[j];
                s += q.x * kv.x + q.y * kv.y + q.z * kv.z + q.w * kv.w;
            }
            acc4[i] = s;
        }
#pragma unroll 4
        for (int c4 = 0; c4 < 16; ++c4) {
            float4 rv = *(const float4*)&rrow[c4 * 4];
#pragma unroll
            for (int i = 0; i < 4; ++i) {
                float4 tv = *(const float4*)&TrUs[w][hh * 4 + i][c4 * 4];
                acc4[i] += rv.x * tv.x + rv.y * tv.y + rv.z * tv.z + rv.w * tv.w;
            }
        }
        const float dd = dist[r * KNBR + kk];
        const float d2 = dd * dd;
#pragma unroll
        for (int i = 0; i < 4; ++i) {
            const int h = hh * 4 + i;
            const float sig2 = __expf(2.f * lsig[h]);
            float lg = acc4[i] * scale - d2 / (2.f * sig2);
            float mx = lg;
#pragma unroll
            for (int m = 16; m >= 1; m >>= 1)
                mx = fmaxf(mx, __shfl_xor(mx, m, 64));
            float pv = __expf(lg - mx);
            float sm = pv;
#pragma unroll
            for (int m = 16; m >= 1; m >>= 1)
                sm += __shfl_xor(sm, m, 64);
            As2[w][kk][h] = pv / sm;
        }
    }

    // ---- P4: o_x = sum_k attn * VtX[idx_k]; overwrites own Q (wave-local) --
    {
        const int h2 = lane >> 3;             // head of f4-chunk lane*4
        const float* vbase = &QKV[(size_t)b * LLEN * QKVLD + 512 + lane * 4];
        float4 ox = {0.f, 0.f, 0.f, 0.f};
#pragma unroll 8
        for (int k = 0; k < KNBR; ++k) {
            const int ik = tkS[w][k];         // wave-uniform
            float4 vv = *(const float4*)&vbase[(size_t)ik * QKVLD];
            const float aw = As2[w][k][h2];
            ox.x += aw * vv.x; ox.y += aw * vv.y;
            ox.z += aw * vv.z; ox.w += aw * vv.w;
        }
        *(float4*)&QsO[w][lane * 4] = ox;
    }

    // ---- P5: u_pe[h][lane] = sum_k attn[h,k]*rpe[k,lane] (wave-local) ----
    {
        float u[NH] = {};
        const float* rbase = &rpe[(size_t)r * KNBR * PEDIM + lane];
#pragma unroll 8
        for (int k = 0; k < KNBR; ++k) {
            const float rv = rbase[(size_t)k * PEDIM];   // coalesced, L1/L2-hot
            float4 a0 = *(const float4*)&As2[w][k][0];
            float4 a1 = *(const float4*)&As2[w][k][4];
            u[0] += a0.x * rv; u[1] += a0.y * rv; u[2] += a0.z * rv; u[3] += a0.w * rv;
            u[4] += a1.x * rv; u[5] += a1.y * rv; u[6] += a1.z * rv; u[7] += a1.w * rv;
        }
#pragma unroll
        for (int h = 0; h < NH; ++h) TrUs[w][h][lane] = u[h];
    }
    __syncthreads();

    // ---- P6: o[i][n] = o_x + u_pe@Wv_pe; thread = col n, all 4 rows ----
    {
        const int n = t, hn = n >> 5;
        float accp[4] = {};
#pragma unroll 4
        for (int c4 = 0; c4 < 16; ++c4) {
            const float* wvp = &Wv[(size_t)(256 + c4 * 4) * 256 + n];
            const float w0 = wvp[0], w1 = wvp[256], w2 = wvp[512], w3 = wvp[768];
#pragma unroll
            for (int i = 0; i < 4; ++i) {
                float4 uv = *(const float4*)&TrUs[i][hn][c4 * 4];
                accp[i] += uv.x * w0 + uv.y * w1 + uv.z * w2 + uv.w * w3;
            }
        }
#pragma unroll
        for (int i = 0; i < 4; ++i) QsO[i][n] += accp[i];   // owner-exclusive
    }
    __syncthreads();

    // ---- P7: out = o @ Wout + b_out (fused final GEMM) ----
    {
        const int n = t;
        float o4[4];
#pragma unroll
        for (int i = 0; i < 4; ++i) o4[i] = b_out[n];
#pragma unroll 4
        for (int c4 = 0; c4 < 64; ++c4) {
            const float* wop = &Wout[(size_t)(c4 * 4) * 256 + n];
            const float w0 = wop[0], w1 = wop[256], w2 = wop[512], w3 = wop[768];
#pragma unroll
            for (int i = 0; i < 4; ++i) {
                float4 ov = *(const float4*)&QsO[i][c4 * 4];   // broadcast
                o4[i] += ov.x * w0 + ov.y * w1 + ov.z * w2 + ov.w * w3;
            }
        }
#pragma unroll
        for (int i = 0; i < 4; ++i)
            out[(size_t)(r0 + i) * DIMX + n] = o4[i];
    }
}

// ---------------------------------------------------------------------------
extern "C" void kernel_launch(void* const* d_in, const int* in_sizes, int n_in,
                              void* d_out, int out_size, void* d_ws, size_t ws_size,
                              hipStream_t stream)
{
    const float* x     = (const float*)d_in[0];
    const int*   topk  = (const int*)  d_in[1];
    const float* rpe   = (const float*)d_in[2];
    const float* dist  = (const float*)d_in[3];
    const float* Wq    = (const float*)d_in[4];
    const float* Wk    = (const float*)d_in[5];
    const float* Wv    = (const float*)d_in[6];
    const float* Wout  = (const float*)d_in[7];
    const float* b_out = (const float*)d_in[8];
    const float* lsig  = (const float*)d_in[9];
    float* out = (float*)d_out;

    float* QKV = (float*)d_ws;   // 8192 x 768 f32 = 24 MB (rewritten every call)

    // K1: QKV = x @ [Wq | Wk_x | Wv_x]   (grid 64 x 6, 256 thr)
    gemm_qkv<<<dim3(NROWS / 128, 6), 256, 0, stream>>>(x, Wq, Wk, Wv, QKV);
    // K2: fused attention + output projection (2048 blocks, 256 thr)
    attn_fused<<<NROWS / 4, 256, 0, stream>>>(QKV, topk, rpe, dist, lsig,
                                              Wk, Wv, Wout, b_out, out);
}